// Round 13
// baseline (749.514 us; speedup 1.0000x reference)
//
#include <hip/hip_runtime.h>
#include <hip/hip_bf16.h>
#include <stdint.h>

#define NB 4
#define CQ 512
#define CK 256
#define TT 4096
#define SCALE_QK 0.21022410381342863f  // 512^-0.25

using bf16x8 = __attribute__((ext_vector_type(8))) short;
using short4v = __attribute__((ext_vector_type(4))) short;
using f32x4  = __attribute__((ext_vector_type(4))) float;
using u32x4  = __attribute__((ext_vector_type(4))) unsigned int;
typedef unsigned short u16;
typedef uint8_t u8;

__device__ __forceinline__ u16 f2bf(float f) {
    union { float f; unsigned u; } v; v.f = f;
    return (u16)((v.u + 0x7fffu + ((v.u >> 16) & 1u)) >> 16);
}
__device__ __forceinline__ float bf2f(u16 h) {
    union { float f; unsigned u; } v; v.u = ((unsigned)h) << 16;
    return v.f;
}
__device__ __forceinline__ u8 f2fp8(float f) {
    return (u8)(__builtin_amdgcn_cvt_pk_fp8_f32(f, f, 0, false) & 0xff);
}
__device__ __forceinline__ bf16x8 pack8(f32x4 a, f32x4 b) {
    bf16x8 r;
    r[0] = (short)f2bf(a[0]); r[1] = (short)f2bf(a[1]);
    r[2] = (short)f2bf(a[2]); r[3] = (short)f2bf(a[3]);
    r[4] = (short)f2bf(b[0]); r[5] = (short)f2bf(b[1]);
    r[6] = (short)f2bf(b[2]); r[7] = (short)f2bf(b[3]);
    return r;
}
// async global->LDS, 16B per lane; LDS dest = wave-uniform base + lane*16
__device__ __forceinline__ void gload_lds16(const void* g, void* l) {
    __builtin_amdgcn_global_load_lds(
        (const __attribute__((address_space(1))) unsigned int*)g,
        (__attribute__((address_space(3))) unsigned int*)l, 16, 0, 0);
}

// ---- weight f32 -> bf16 conversion (optionally scale first scale_until elements) ----
__global__ __launch_bounds__(256) void wconv_kernel(const float* __restrict__ src,
        u16* __restrict__ dst, int n, int scale_until) {
    int i = (blockIdx.x * 256 + threadIdx.x) * 8;
    if (i >= n) return;
    f32x4 a = *(const f32x4*)(src + i);
    f32x4 c = *(const f32x4*)(src + i + 4);
    if (i < scale_until) {
        a *= SCALE_QK;
        c *= SCALE_QK;
    }
    *(bf16x8*)(dst + i) = pack8(a, c);
}

// ---- 2x2 avg pool of key_feat (b,256,128,128) -> kdsT (b,4096,256) bf16 ----
__global__ __launch_bounds__(256) void pool_tr_kernel(const float* __restrict__ kf,
                                                      u16* __restrict__ kdsT) {
    int h = blockIdx.x, b = blockIdx.y;
    __shared__ u16 tile[64][264];  // [w][c], padded
    for (int idx = threadIdx.x; idx < 32 * 256; idx += 256) {
        int wp = idx & 31, c = idx >> 5;
        const float* base = kf + (((size_t)b * CK + c) * 128 + 2 * h) * 128 + 4 * wp;
        f32x4 r0 = *(const f32x4*)base;
        f32x4 r1 = *(const f32x4*)(base + 128);
        tile[2 * wp][c]     = f2bf(0.25f * (r0[0] + r0[1] + r1[0] + r1[1]));
        tile[2 * wp + 1][c] = f2bf(0.25f * (r0[2] + r0[3] + r1[2] + r1[3]));
    }
    __syncthreads();
    for (int idx = threadIdx.x; idx < 64 * 32; idx += 256) {
        int w = idx >> 5, cg = (idx & 31) << 3;
        *(u32x4*)(kdsT + ((size_t)b * TT + h * 64 + w) * CK + cg) = *(const u32x4*)&tile[w][cg];
    }
}

// ---- GroupNorm stats -> per-channel scale/shift (folded affine) ----
template <int ISBF>
__global__ __launch_bounds__(256) void gn_stats_kernel(const void* __restrict__ xv,
        const float* __restrict__ gw, const float* __restrict__ gb,
        float* __restrict__ sc, float* __restrict__ sh) {
    int g = blockIdx.x, b = blockIdx.y;
    size_t base = ((size_t)b * CQ + g * 16) * TT;
    float s = 0.f, q = 0.f;
    for (int i = threadIdx.x * 4; i < 16 * TT; i += 256 * 4) {
        float v0, v1, v2, v3;
        if constexpr (ISBF) {
            const u16* x = (const u16*)xv;
            uint2 u = *(const uint2*)(x + base + i);
            v0 = bf2f((u16)(u.x & 0xffff)); v1 = bf2f((u16)(u.x >> 16));
            v2 = bf2f((u16)(u.y & 0xffff)); v3 = bf2f((u16)(u.y >> 16));
        } else {
            const float* x = (const float*)xv;
            f32x4 v = *(const f32x4*)(x + base + i);
            v0 = v[0]; v1 = v[1]; v2 = v[2]; v3 = v[3];
        }
        s += v0 + v1 + v2 + v3;
        q += v0 * v0 + v1 * v1 + v2 * v2 + v3 * v3;
    }
#pragma unroll
    for (int d = 1; d < 64; d <<= 1) { s += __shfl_xor(s, d, 64); q += __shfl_xor(q, d, 64); }
    __shared__ float shs[4], shq[4];
    int wid = threadIdx.x >> 6;
    if ((threadIdx.x & 63) == 0) { shs[wid] = s; shq[wid] = q; }
    __syncthreads();
    if (threadIdx.x < 16) {
        float S = shs[0] + shs[1] + shs[2] + shs[3];
        float Q = shq[0] + shq[1] + shq[2] + shq[3];
        const float inv = 1.f / (16.f * TT);
        float mean = S * inv, var = Q * inv - mean * mean;
        float rstd = rsqrtf(var + 1e-5f);
        int c = g * 16 + threadIdx.x;
        float w = gw[c] * rstd;
        sc[b * CQ + c] = w;
        sh[b * CQ + c] = gb[c] - mean * w;
    }
}

// ---- affine + transpose: in (b,512,T) -> out (b,T,512) bf16 ----
template <int ISBF>
__global__ __launch_bounds__(256) void affine_tr_kernel(const void* __restrict__ xv,
        const float* __restrict__ sc, const float* __restrict__ sh, u16* __restrict__ out) {
    int t0 = blockIdx.x * 64, c0 = blockIdx.y * 64, b = blockIdx.z;
    __shared__ u16 tile[64][72];  // [t][c]
    for (int idx = threadIdx.x; idx < 16 * 64; idx += 256) {
        int tq = idx & 15, cl = idx >> 4;
        int c = c0 + cl;
        float w = sc[b * CQ + c], z = sh[b * CQ + c];
        float v[4];
        if constexpr (ISBF) {
            short4v u = *(const short4v*)((const u16*)xv + ((size_t)b * CQ + c) * TT + t0 + 4 * tq);
#pragma unroll
            for (int j = 0; j < 4; j++) v[j] = bf2f((u16)u[j]);
        } else {
            f32x4 u = *(const f32x4*)((const float*)xv + ((size_t)b * CQ + c) * TT + t0 + 4 * tq);
#pragma unroll
            for (int j = 0; j < 4; j++) v[j] = u[j];
        }
#pragma unroll
        for (int j = 0; j < 4; j++) tile[4 * tq + j][cl] = f2bf(v[j] * w + z);
    }
    __syncthreads();
    for (int idx = threadIdx.x; idx < 64 * 8; idx += 256) {
        int tl = idx >> 3, cg = (idx & 7) << 3;
        *(u32x4*)(out + ((size_t)b * TT + t0 + tl) * CQ + c0 + cg) = *(const u32x4*)&tile[tl][cg];
    }
}

// ---- staged GEMM: 128o x 128t tile, BK=64, double-buffered LDS, global_load_lds ----
// EPI 0: bf16 store. EPI 1: +bias, fp8 store (vv8). EPI 2: +bias+GN(query) res, f32.
// SWAP=1 (qk): D[t][o]; v=acc+bias[o]*SCALE_QK; fp8 store -> qq8 (o<512) / kk8.
template <int EPI, int CONCAT, int SWAP>
__global__ __launch_bounds__(256) void gemm_st_kernel(
        const u16* __restrict__ Wb, const u16* __restrict__ X1, const u16* __restrict__ X2,
        int Ktot, const float* __restrict__ bias,
        void* __restrict__ outb, void* __restrict__ outb2, float* __restrict__ outf,
        const float* __restrict__ query, const float* __restrict__ qsc,
        const float* __restrict__ qsh) {
    int b = blockIdx.z;
    int o0 = blockIdx.x * 128, t0 = blockIdx.y * 128;
    int wid = threadIdx.x >> 6, lane = threadIdx.x & 63;
    int lr = lane & 15, lg = lane >> 4;
    int osub = (wid >> 1) * 64, tsub = (wid & 1) * 64;

    __shared__ u16 Wl[2][128][64];
    __shared__ u16 Xl[2][128][64];

    const int Kx = CONCAT ? 512 : Ktot;
    int srow = lane >> 3;
    int sxw = ((lane & 7) ^ srow) << 4;
    int xr = (lr & 7) << 4;

    f32x4 acc[4][4];
#pragma unroll
    for (int i = 0; i < 4; i++)
#pragma unroll
        for (int j = 0; j < 4; j++) acc[i][j] = f32x4{0.f, 0.f, 0.f, 0.f};

    int nk = Ktot >> 6;

#define STAGE_TILE(KC, BUF)                                                          \
    do {                                                                             \
        int c0_ = (KC) << 6;                                                         \
        const u16* xs_;                                                              \
        if (CONCAT && c0_ >= 512) xs_ = X2 + ((size_t)b * TT) * 512 + (c0_ - 512);   \
        else if (CONCAT)          xs_ = X1 + ((size_t)b * TT) * 512 + c0_;           \
        else                      xs_ = X1 + ((size_t)b * TT) * (size_t)Ktot + c0_;  \
        const char* xb_ = (const char*)(xs_ + (size_t)(t0 + wid * 32) * Kx) + sxw;   \
        const char* wb_ = (const char*)(Wb + (size_t)(o0 + wid * 32) * Ktot + c0_) + sxw; \
        _Pragma("unroll")                                                            \
        for (int i_ = 0; i_ < 4; i_++) {                                             \
            gload_lds16(xb_ + (size_t)(i_ * 8 + srow) * (Kx * 2),                    \
                        &Xl[BUF][wid * 32 + i_ * 8][0]);                             \
            gload_lds16(wb_ + (size_t)(i_ * 8 + srow) * (Ktot * 2),                  \
                        &Wl[BUF][wid * 32 + i_ * 8][0]);                             \
        }                                                                            \
    } while (0)

    STAGE_TILE(0, 0);
    __syncthreads();
    int cur = 0;
    for (int kc = 0; kc < nk; kc++) {
        if (kc + 1 < nk) STAGE_TILE(kc + 1, cur ^ 1);
#pragma unroll
        for (int kk = 0; kk < 2; kk++) {
            int boff = (kk * 64 + lg * 16) ^ xr;
            bf16x8 am[4], bn[4];
#pragma unroll
            for (int mi = 0; mi < 4; mi++) {
                if (SWAP) am[mi] = *(const bf16x8*)((const char*)&Xl[cur][tsub + mi * 16 + lr][0] + boff);
                else      am[mi] = *(const bf16x8*)((const char*)&Wl[cur][osub + mi * 16 + lr][0] + boff);
            }
#pragma unroll
            for (int ni = 0; ni < 4; ni++) {
                if (SWAP) bn[ni] = *(const bf16x8*)((const char*)&Wl[cur][osub + ni * 16 + lr][0] + boff);
                else      bn[ni] = *(const bf16x8*)((const char*)&Xl[cur][tsub + ni * 16 + lr][0] + boff);
            }
#pragma unroll
            for (int mi = 0; mi < 4; mi++)
#pragma unroll
                for (int ni = 0; ni < 4; ni++)
                    acc[mi][ni] = __builtin_amdgcn_mfma_f32_16x16x32_bf16(am[mi], bn[ni], acc[mi][ni], 0, 0, 0);
        }
        __syncthreads();
        cur ^= 1;
    }
#undef STAGE_TILE

    if (SWAP) {
        u8* qq8 = (u8*)outb;
        u8* kk8 = (u8*)outb2;
#pragma unroll
        for (int mi = 0; mi < 4; mi++)
#pragma unroll
            for (int ni = 0; ni < 4; ni++)
#pragma unroll
                for (int reg = 0; reg < 4; reg++) {
                    int t = t0 + tsub + mi * 16 + 4 * lg + reg;
                    int o = o0 + osub + ni * 16 + lr;
                    float v = acc[mi][ni][reg] + bias[o] * SCALE_QK;
                    if (o < 512) qq8[((size_t)b * TT + t) * 512 + o] = f2fp8(v);
                    else         kk8[((size_t)b * TT + t) * 512 + (o - 512)] = f2fp8(v);
                }
    } else {
#pragma unroll
        for (int mi = 0; mi < 4; mi++)
#pragma unroll
            for (int reg = 0; reg < 4; reg++) {
                int o = o0 + osub + mi * 16 + 4 * lg + reg;
                float bv = (EPI >= 1) ? bias[o] : 0.f;
#pragma unroll
                for (int ni = 0; ni < 4; ni++) {
                    int t = t0 + tsub + ni * 16 + lr;
                    size_t oidx = ((size_t)b * CQ + o) * TT + t;
                    float v = acc[mi][ni][reg] + bv;
                    if (EPI == 2) {
                        outf[oidx] = v + query[oidx] * qsc[b * CQ + o] + qsh[b * CQ + o];
                    } else if (EPI == 1) {
                        ((u8*)outb)[oidx] = f2fp8(v);
                    } else {
                        ((u16*)outb)[oidx] = f2bf(v);
                    }
                }
            }
    }
}

// ---- flash attention v12: fp8 K/V/Q/P + split-C -> 53KB LDS, ~118 regs, 2 blocks/CU ----
// Grid (2, 64, NB): x = c-half (paired blocks adjacent -> WM L2-shared), y = t-block, z = b.
// 8 waves: tb = wid>>1 (16t), cb = wid&1. QK role: 16t x 32s (sb=cb). PV: 16t x 128c.
// QK + softmax computed redundantly per c-half; PV covers chalf*256 + cb*128 + 128c.
__global__ __launch_bounds__(512, 4) void flash_kernel(
        const u8* __restrict__ qq8, const u8* __restrict__ kk8,
        const u8* __restrict__ vv8, const float* __restrict__ WM,
        u16* __restrict__ aT) {
    int chalf = blockIdx.x;
    int T0 = blockIdx.y * 64;
    int b = blockIdx.z;
    int wid = threadIdx.x >> 6, lane = threadIdx.x & 63;
    int lr = lane & 15, lg = lane >> 4;
    int tb = wid >> 1, cb = wid & 1;

    __shared__ u8 K_lds[64][512];    // 32KB, 16B-chunk swizzled by (s&7)
    __shared__ u8 V_lds[256][64];    // 16KB, chunk swizzled by (c&3)
    __shared__ u8 p_lds[64][64];     // 4KB, chunk swizzled by (t&3)
    __shared__ float ex_max[64][2];
    __shared__ float ex_sum[64][2];

    // Q fp8 fragments: row = T0+16tb+lr, k = kc*32 + lg*8 (8 bytes -> 2 VGPR)
    long qf[16];
    {
        const u8* qrow = qq8 + ((size_t)b * TT + T0 + 16 * tb + lr) * 512 + lg * 8;
#pragma unroll
        for (int kc = 0; kc < 16; kc++) qf[kc] = *(const long*)(qrow + kc * 32);
    }
    f32x4 acc[8];
#pragma unroll
    for (int i = 0; i < 8; i++) acc[i] = f32x4{0.f, 0.f, 0.f, 0.f};
    float m[4], l[4];
#pragma unroll
    for (int r = 0; r < 4; r++) { m[r] = -1e30f; l[r] = 0.f; }

    const float* wmrow = WM + ((size_t)b * TT + T0 + 16 * tb + 4 * lg) * TT + 32 * cb + lr;
    const u8* kbase = kk8 + (size_t)b * TT * 512;
    const u8* vbase = vv8 + ((size_t)b * CQ + chalf * 256) * TT;
    int myt = 16 * tb + 4 * lg;

    for (int s0 = 0; s0 < TT; s0 += 64) {
        __syncthreads();  // bar1: prev tile consumed
        // stage K: 2 rows (512B each) per instr, 4 instr/wave
#pragma unroll
        for (int i = 0; i < 4; i++) {
            int r0 = wid * 8 + i * 2;
            int s = r0 + (lane >> 5);
            gload_lds16(kbase + (size_t)(s0 + s) * 512 + (((lane & 31) ^ (s & 7)) << 4),
                        &K_lds[r0][0]);
        }
        // stage V: 16 rows (64B each) per instr, 2 instr/wave (256 rows total)
#pragma unroll
        for (int i = 0; i < 2; i++) {
            int c0 = wid * 32 + i * 16;
            int c = c0 + (lane >> 2);
            gload_lds16(vbase + (size_t)c * TT + s0 + (((lane & 3) ^ (c & 3)) << 4),
                        &V_lds[c0][0]);
        }
        float wmv[2][4];
#pragma unroll
        for (int fs = 0; fs < 2; fs++)
#pragma unroll
            for (int reg = 0; reg < 4; reg++)
                wmv[fs][reg] = wmrow[(size_t)reg * TT + s0 + fs * 16];
        __syncthreads();  // bar2: K/V staged

        // QK: S[16t x 32s], fp8 MFMA
        f32x4 sacc[2];
        sacc[0] = f32x4{0.f, 0.f, 0.f, 0.f};
        sacc[1] = f32x4{0.f, 0.f, 0.f, 0.f};
#pragma unroll
        for (int kc = 0; kc < 16; kc++) {
#pragma unroll
            for (int fs = 0; fs < 2; fs++) {
                int srow = 32 * cb + fs * 16 + lr;
                long kfr = *(const long*)(&K_lds[srow][0] +
                            ((((kc << 1) | (lg >> 1)) ^ (srow & 7)) << 4) + ((lg & 1) << 3));
                sacc[fs] = __builtin_amdgcn_mfma_f32_16x16x32_fp8_fp8(qf[kc], kfr, sacc[fs], 0, 0, 0);
            }
        }
        // logits = WM*S ; row max over this wave's 32 s
        float lgt[2][4], pmax[4];
#pragma unroll
        for (int r = 0; r < 4; r++) pmax[r] = -3e38f;
#pragma unroll
        for (int fs = 0; fs < 2; fs++)
#pragma unroll
            for (int reg = 0; reg < 4; reg++) {
                float v = sacc[fs][reg] * wmv[fs][reg];
                lgt[fs][reg] = v;
                pmax[reg] = fmaxf(pmax[reg], v);
            }
#pragma unroll
        for (int d = 1; d < 16; d <<= 1)
#pragma unroll
            for (int reg = 0; reg < 4; reg++)
                pmax[reg] = fmaxf(pmax[reg], __shfl_xor(pmax[reg], d, 64));
        if (lr == 0) {
#pragma unroll
            for (int reg = 0; reg < 4; reg++) ex_max[myt + reg][cb] = pmax[reg];
        }
        __syncthreads();  // bar3: maxes exchanged
        float fac[4], rsum[4];
#pragma unroll
        for (int reg = 0; reg < 4; reg++) {
            int t = myt + reg;
            float mn = fmaxf(m[reg], fmaxf(ex_max[t][0], ex_max[t][1]));
            fac[reg] = __expf(m[reg] - mn);
            m[reg] = mn;
            rsum[reg] = 0.f;
        }
#pragma unroll
        for (int fs = 0; fs < 2; fs++)
#pragma unroll
            for (int reg = 0; reg < 4; reg++) {
                float p = __expf(lgt[fs][reg] - m[reg]);
                rsum[reg] += p;
                int t = myt + reg;
                // s = 32*cb + fs*16 + lr ; chunk16 = (2cb+fs) ^ (t&3) ; byte-in-chunk = lr
                p_lds[t][((((cb << 1) | fs) ^ (t & 3)) << 4) + lr] = f2fp8(p);
            }
#pragma unroll
        for (int d = 1; d < 16; d <<= 1)
#pragma unroll
            for (int reg = 0; reg < 4; reg++)
                rsum[reg] += __shfl_xor(rsum[reg], d, 64);
        if (lr == 0) {
#pragma unroll
            for (int reg = 0; reg < 4; reg++) ex_sum[myt + reg][cb] = rsum[reg];
        }
        __syncthreads();  // bar4: P + sums ready
#pragma unroll
        for (int reg = 0; reg < 4; reg++) {
            int t = myt + reg;
            l[reg] = l[reg] * fac[reg] + ex_sum[t][0] + ex_sum[t][1];
        }
#pragma unroll
        for (int nc = 0; nc < 8; nc++)
#pragma unroll
            for (int reg = 0; reg < 4; reg++) acc[nc][reg] *= fac[reg];
        // PV: acc[16t x 128c] += P[16t x 64s] * V[128c x 64s], fp8 MFMA
#pragma unroll
        for (int ks = 0; ks < 2; ks++) {
            int prow = 16 * tb + lr;
            long pa = *(const long*)(&p_lds[prow][0] +
                        ((((ks << 1) | (lg >> 1)) ^ (prow & 3)) << 4) + ((lg & 1) << 3));
#pragma unroll
            for (int nc = 0; nc < 8; nc++) {
                int vr = cb * 128 + nc * 16 + lr;
                long vf = *(const long*)(&V_lds[vr][0] +
                            ((((ks << 1) | (lg >> 1)) ^ (vr & 3)) << 4) + ((lg & 1) << 3));
                acc[nc] = __builtin_amdgcn_mfma_f32_16x16x32_fp8_fp8(pa, vf, acc[nc], 0, 0, 0);
            }
        }
    }
    // epilogue: normalize + store bf16
    float inv[4];
#pragma unroll
    for (int reg = 0; reg < 4; reg++) inv[reg] = 1.f / l[reg];
#pragma unroll
    for (int nc = 0; nc < 8; nc++)
#pragma unroll
        for (int reg = 0; reg < 4; reg++) {
            int t = T0 + myt + reg;
            int c = chalf * 256 + cb * 128 + nc * 16 + lr;
            aT[((size_t)b * TT + t) * CQ + c] = f2bf(acc[nc][reg] * inv[reg]);
        }
}

extern "C" void kernel_launch(void* const* d_in, const int* in_sizes, int n_in,
                              void* d_out, int out_size, void* d_ws, size_t ws_size,
                              hipStream_t stream) {
    const float* key_feat = (const float*)d_in[0];
    const float* query    = (const float*)d_in[1];
    const float* WM       = (const float*)d_in[2];
    const float* kpw      = (const float*)d_in[3];
    const float* norm_w   = (const float*)d_in[4];
    const float* norm_b   = (const float*)d_in[5];
    const float* qkv_w    = (const float*)d_in[6];
    const float* qkv_b    = (const float*)d_in[7];
    const float* proj_w   = (const float*)d_in[8];
    const float* proj_b   = (const float*)d_in[9];
    float* out = (float*)d_out;
    char* ws = (char*)d_ws;

    u16* kdsT = (u16*)(ws);                 // [0, 8.4M)   dead after kraw gemm
    u16* kraw = (u16*)(ws + 8388608);       // [8.4, 25.2M) dead after affine#2
    u16* qnT  = (u16*)(ws + 25165824);      // dead after qkv gemms
    u16* knT  = (u16*)(ws + 41943040);      // dead after qkv gemms
    u8*  qq8  = (u8*)(ws + 58720256);       // 8.4 MB fp8
    u8*  kk8  = (u8*)(ws + 67108864);       // 8.4 MB fp8
    u8*  vv8  = (u8*)(ws + 75497472);       // 8.4 MB fp8
    u16* aT   = (u16*)(ws);                 // [0, 16.8M) over kdsT+kraw head (dead by flash)
    u16* wqkv = (u16*)(ws + 16777216);      // over kraw tail, written after affine#2
    u16* wproj= (u16*)(ws + 19922944);
    float* qsc = (float*)(ws + 109051904);
    float* qsh = qsc + NB * CQ;
    float* ksc = qsh + NB * CQ;
    float* ksh = ksc + NB * CQ;
    u16* wkp  = (u16*)(ws + 109084672);     // 256KB

    // 0. convert key_proj_w to bf16
    wconv_kernel<<<64, 256, 0, stream>>>(kpw, wkp, 512 * 256, 0);
    // 1. pool + transpose
    pool_tr_kernel<<<dim3(64, NB), 256, 0, stream>>>(key_feat, kdsT);
    // 2. k_raw = key_proj_w @ kds   (staged GEMM)
    gemm_st_kernel<0, 0, 0><<<dim3(4, 32, NB), 256, 0, stream>>>(
        wkp, kdsT, nullptr, CK, nullptr, kraw, nullptr, nullptr, nullptr, nullptr, nullptr);
    // 3. group-norm stats
    gn_stats_kernel<0><<<dim3(32, NB), 256, 0, stream>>>(query, norm_w, norm_b, qsc, qsh);
    gn_stats_kernel<1><<<dim3(32, NB), 256, 0, stream>>>(kraw, norm_w, norm_b, ksc, ksh);
    // 4. normalized, transposed activations
    affine_tr_kernel<0><<<dim3(64, 8, NB), 256, 0, stream>>>(query, qsc, qsh, qnT);
    affine_tr_kernel<1><<<dim3(64, 8, NB), 256, 0, stream>>>(kraw, ksc, ksh, knT);
    // 4b. convert qkv_w (q/k rows pre-scaled) + proj_w to bf16 (kraw now dead)
    wconv_kernel<<<768, 256, 0, stream>>>(qkv_w, wqkv, 1536 * 1024, 1024 * 1024);
    wconv_kernel<<<128, 256, 0, stream>>>(proj_w, wproj, 512 * 512, 0);
    // 5. qkv projection: qq/kk swapped -> fp8, vv -> fp8
    gemm_st_kernel<1, 1, 1><<<dim3(8, 32, NB), 256, 0, stream>>>(
        wqkv, qnT, knT, 1024, qkv_b, qq8, kk8, nullptr, nullptr, nullptr, nullptr);
    gemm_st_kernel<1, 1, 0><<<dim3(4, 32, NB), 256, 0, stream>>>(
        wqkv + (size_t)1024 * 1024, qnT, knT, 1024, qkv_b + 1024, vv8, nullptr,
        nullptr, nullptr, nullptr, nullptr);
    // 6. flash attention (v12: fp8 + split-C, 2 blocks/CU)
    flash_kernel<<<dim3(2, 64, NB), 512, 0, stream>>>(qq8, kk8, vv8, WM, aT);
    // 7. out = GN(query) + proj_w @ a + proj_b
    gemm_st_kernel<2, 0, 0><<<dim3(4, 32, NB), 256, 0, stream>>>(
        wproj, aT, nullptr, CQ, proj_b, nullptr, nullptr, out, query, qsc, qsh);
}

// Round 14
// 637.260 us; speedup vs baseline: 1.1762x; 1.1762x over previous
//
#include <hip/hip_runtime.h>
#include <hip/hip_bf16.h>
#include <stdint.h>

#define NB 4
#define CQ 512
#define CK 256
#define TT 4096
#define SCALE_QK 0.21022410381342863f  // 512^-0.25

using bf16x8 = __attribute__((ext_vector_type(8))) short;
using short4v = __attribute__((ext_vector_type(4))) short;
using f32x4  = __attribute__((ext_vector_type(4))) float;
using u32x4  = __attribute__((ext_vector_type(4))) unsigned int;
typedef unsigned short u16;
typedef uint8_t u8;

__device__ __forceinline__ u16 f2bf(float f) {
    union { float f; unsigned u; } v; v.f = f;
    return (u16)((v.u + 0x7fffu + ((v.u >> 16) & 1u)) >> 16);
}
__device__ __forceinline__ float bf2f(u16 h) {
    union { float f; unsigned u; } v; v.u = ((unsigned)h) << 16;
    return v.f;
}
__device__ __forceinline__ u8 f2fp8(float f) {
    return (u8)(__builtin_amdgcn_cvt_pk_fp8_f32(f, f, 0, false) & 0xff);
}
__device__ __forceinline__ bf16x8 pack8(f32x4 a, f32x4 b) {
    bf16x8 r;
    r[0] = (short)f2bf(a[0]); r[1] = (short)f2bf(a[1]);
    r[2] = (short)f2bf(a[2]); r[3] = (short)f2bf(a[3]);
    r[4] = (short)f2bf(b[0]); r[5] = (short)f2bf(b[1]);
    r[6] = (short)f2bf(b[2]); r[7] = (short)f2bf(b[3]);
    return r;
}
// async global->LDS, 16B per lane; LDS dest = wave-uniform base + lane*16
__device__ __forceinline__ void gload_lds16(const void* g, void* l) {
    __builtin_amdgcn_global_load_lds(
        (const __attribute__((address_space(1))) unsigned int*)g,
        (__attribute__((address_space(3))) unsigned int*)l, 16, 0, 0);
}

// ---- weight f32 -> bf16 conversion (optionally scale first scale_until elements) ----
__global__ __launch_bounds__(256) void wconv_kernel(const float* __restrict__ src,
        u16* __restrict__ dst, int n, int scale_until) {
    int i = (blockIdx.x * 256 + threadIdx.x) * 8;
    if (i >= n) return;
    f32x4 a = *(const f32x4*)(src + i);
    f32x4 c = *(const f32x4*)(src + i + 4);
    if (i < scale_until) {
        a *= SCALE_QK;
        c *= SCALE_QK;
    }
    *(bf16x8*)(dst + i) = pack8(a, c);
}

// ---- 2x2 avg pool of key_feat (b,256,128,128) -> kdsT (b,4096,256) bf16 ----
__global__ __launch_bounds__(256) void pool_tr_kernel(const float* __restrict__ kf,
                                                      u16* __restrict__ kdsT) {
    int h = blockIdx.x, b = blockIdx.y;
    __shared__ u16 tile[64][264];  // [w][c], padded
    for (int idx = threadIdx.x; idx < 32 * 256; idx += 256) {
        int wp = idx & 31, c = idx >> 5;
        const float* base = kf + (((size_t)b * CK + c) * 128 + 2 * h) * 128 + 4 * wp;
        f32x4 r0 = *(const f32x4*)base;
        f32x4 r1 = *(const f32x4*)(base + 128);
        tile[2 * wp][c]     = f2bf(0.25f * (r0[0] + r0[1] + r1[0] + r1[1]));
        tile[2 * wp + 1][c] = f2bf(0.25f * (r0[2] + r0[3] + r1[2] + r1[3]));
    }
    __syncthreads();
    for (int idx = threadIdx.x; idx < 64 * 32; idx += 256) {
        int w = idx >> 5, cg = (idx & 31) << 3;
        *(u32x4*)(kdsT + ((size_t)b * TT + h * 64 + w) * CK + cg) = *(const u32x4*)&tile[w][cg];
    }
}

// ---- GroupNorm stats -> per-channel scale/shift (folded affine) ----
template <int ISBF>
__global__ __launch_bounds__(256) void gn_stats_kernel(const void* __restrict__ xv,
        const float* __restrict__ gw, const float* __restrict__ gb,
        float* __restrict__ sc, float* __restrict__ sh) {
    int g = blockIdx.x, b = blockIdx.y;
    size_t base = ((size_t)b * CQ + g * 16) * TT;
    float s = 0.f, q = 0.f;
    for (int i = threadIdx.x * 4; i < 16 * TT; i += 256 * 4) {
        float v0, v1, v2, v3;
        if constexpr (ISBF) {
            const u16* x = (const u16*)xv;
            uint2 u = *(const uint2*)(x + base + i);
            v0 = bf2f((u16)(u.x & 0xffff)); v1 = bf2f((u16)(u.x >> 16));
            v2 = bf2f((u16)(u.y & 0xffff)); v3 = bf2f((u16)(u.y >> 16));
        } else {
            const float* x = (const float*)xv;
            f32x4 v = *(const f32x4*)(x + base + i);
            v0 = v[0]; v1 = v[1]; v2 = v[2]; v3 = v[3];
        }
        s += v0 + v1 + v2 + v3;
        q += v0 * v0 + v1 * v1 + v2 * v2 + v3 * v3;
    }
#pragma unroll
    for (int d = 1; d < 64; d <<= 1) { s += __shfl_xor(s, d, 64); q += __shfl_xor(q, d, 64); }
    __shared__ float shs[4], shq[4];
    int wid = threadIdx.x >> 6;
    if ((threadIdx.x & 63) == 0) { shs[wid] = s; shq[wid] = q; }
    __syncthreads();
    if (threadIdx.x < 16) {
        float S = shs[0] + shs[1] + shs[2] + shs[3];
        float Q = shq[0] + shq[1] + shq[2] + shq[3];
        const float inv = 1.f / (16.f * TT);
        float mean = S * inv, var = Q * inv - mean * mean;
        float rstd = rsqrtf(var + 1e-5f);
        int c = g * 16 + threadIdx.x;
        float w = gw[c] * rstd;
        sc[b * CQ + c] = w;
        sh[b * CQ + c] = gb[c] - mean * w;
    }
}

// ---- affine + transpose: in (b,512,T) -> out (b,T,512) bf16 ----
template <int ISBF>
__global__ __launch_bounds__(256) void affine_tr_kernel(const void* __restrict__ xv,
        const float* __restrict__ sc, const float* __restrict__ sh, u16* __restrict__ out) {
    int t0 = blockIdx.x * 64, c0 = blockIdx.y * 64, b = blockIdx.z;
    __shared__ u16 tile[64][72];  // [t][c]
    for (int idx = threadIdx.x; idx < 16 * 64; idx += 256) {
        int tq = idx & 15, cl = idx >> 4;
        int c = c0 + cl;
        float w = sc[b * CQ + c], z = sh[b * CQ + c];
        float v[4];
        if constexpr (ISBF) {
            short4v u = *(const short4v*)((const u16*)xv + ((size_t)b * CQ + c) * TT + t0 + 4 * tq);
#pragma unroll
            for (int j = 0; j < 4; j++) v[j] = bf2f((u16)u[j]);
        } else {
            f32x4 u = *(const f32x4*)((const float*)xv + ((size_t)b * CQ + c) * TT + t0 + 4 * tq);
#pragma unroll
            for (int j = 0; j < 4; j++) v[j] = u[j];
        }
#pragma unroll
        for (int j = 0; j < 4; j++) tile[4 * tq + j][cl] = f2bf(v[j] * w + z);
    }
    __syncthreads();
    for (int idx = threadIdx.x; idx < 64 * 8; idx += 256) {
        int tl = idx >> 3, cg = (idx & 7) << 3;
        *(u32x4*)(out + ((size_t)b * TT + t0 + tl) * CQ + c0 + cg) = *(const u32x4*)&tile[tl][cg];
    }
}

// ---- staged GEMM: 128o x 128t tile, BK=64, double-buffered LDS, global_load_lds ----
// EPI 0: bf16 store. EPI 1: +bias, fp8 store (vv8). EPI 2: +bias+GN(query) res, f32.
// SWAP=1 (qk): D[t][o]; v=acc+bias[o]*SCALE_QK; fp8 store -> qq8 (o<512) / kk8.
template <int EPI, int CONCAT, int SWAP>
__global__ __launch_bounds__(256) void gemm_st_kernel(
        const u16* __restrict__ Wb, const u16* __restrict__ X1, const u16* __restrict__ X2,
        int Ktot, const float* __restrict__ bias,
        void* __restrict__ outb, void* __restrict__ outb2, float* __restrict__ outf,
        const float* __restrict__ query, const float* __restrict__ qsc,
        const float* __restrict__ qsh) {
    int b = blockIdx.z;
    int o0 = blockIdx.x * 128, t0 = blockIdx.y * 128;
    int wid = threadIdx.x >> 6, lane = threadIdx.x & 63;
    int lr = lane & 15, lg = lane >> 4;
    int osub = (wid >> 1) * 64, tsub = (wid & 1) * 64;

    __shared__ u16 Wl[2][128][64];
    __shared__ u16 Xl[2][128][64];

    const int Kx = CONCAT ? 512 : Ktot;
    int srow = lane >> 3;
    int sxw = ((lane & 7) ^ srow) << 4;
    int xr = (lr & 7) << 4;

    f32x4 acc[4][4];
#pragma unroll
    for (int i = 0; i < 4; i++)
#pragma unroll
        for (int j = 0; j < 4; j++) acc[i][j] = f32x4{0.f, 0.f, 0.f, 0.f};

    int nk = Ktot >> 6;

#define STAGE_TILE(KC, BUF)                                                          \
    do {                                                                             \
        int c0_ = (KC) << 6;                                                         \
        const u16* xs_;                                                              \
        if (CONCAT && c0_ >= 512) xs_ = X2 + ((size_t)b * TT) * 512 + (c0_ - 512);   \
        else if (CONCAT)          xs_ = X1 + ((size_t)b * TT) * 512 + c0_;           \
        else                      xs_ = X1 + ((size_t)b * TT) * (size_t)Ktot + c0_;  \
        const char* xb_ = (const char*)(xs_ + (size_t)(t0 + wid * 32) * Kx) + sxw;   \
        const char* wb_ = (const char*)(Wb + (size_t)(o0 + wid * 32) * Ktot + c0_) + sxw; \
        _Pragma("unroll")                                                            \
        for (int i_ = 0; i_ < 4; i_++) {                                             \
            gload_lds16(xb_ + (size_t)(i_ * 8 + srow) * (Kx * 2),                    \
                        &Xl[BUF][wid * 32 + i_ * 8][0]);                             \
            gload_lds16(wb_ + (size_t)(i_ * 8 + srow) * (Ktot * 2),                  \
                        &Wl[BUF][wid * 32 + i_ * 8][0]);                             \
        }                                                                            \
    } while (0)

    STAGE_TILE(0, 0);
    __syncthreads();
    int cur = 0;
    for (int kc = 0; kc < nk; kc++) {
        if (kc + 1 < nk) STAGE_TILE(kc + 1, cur ^ 1);
#pragma unroll
        for (int kk = 0; kk < 2; kk++) {
            int boff = (kk * 64 + lg * 16) ^ xr;
            bf16x8 am[4], bn[4];
#pragma unroll
            for (int mi = 0; mi < 4; mi++) {
                if (SWAP) am[mi] = *(const bf16x8*)((const char*)&Xl[cur][tsub + mi * 16 + lr][0] + boff);
                else      am[mi] = *(const bf16x8*)((const char*)&Wl[cur][osub + mi * 16 + lr][0] + boff);
            }
#pragma unroll
            for (int ni = 0; ni < 4; ni++) {
                if (SWAP) bn[ni] = *(const bf16x8*)((const char*)&Wl[cur][osub + ni * 16 + lr][0] + boff);
                else      bn[ni] = *(const bf16x8*)((const char*)&Xl[cur][tsub + ni * 16 + lr][0] + boff);
            }
#pragma unroll
            for (int mi = 0; mi < 4; mi++)
#pragma unroll
                for (int ni = 0; ni < 4; ni++)
                    acc[mi][ni] = __builtin_amdgcn_mfma_f32_16x16x32_bf16(am[mi], bn[ni], acc[mi][ni], 0, 0, 0);
        }
        __syncthreads();
        cur ^= 1;
    }
#undef STAGE_TILE

    if (SWAP) {
        u8* qq8 = (u8*)outb;
        u8* kk8 = (u8*)outb2;
#pragma unroll
        for (int mi = 0; mi < 4; mi++)
#pragma unroll
            for (int ni = 0; ni < 4; ni++)
#pragma unroll
                for (int reg = 0; reg < 4; reg++) {
                    int t = t0 + tsub + mi * 16 + 4 * lg + reg;
                    int o = o0 + osub + ni * 16 + lr;
                    float v = acc[mi][ni][reg] + bias[o] * SCALE_QK;
                    if (o < 512) qq8[((size_t)b * TT + t) * 512 + o] = f2fp8(v);
                    else         kk8[((size_t)b * TT + t) * 512 + (o - 512)] = f2fp8(v);
                }
    } else {
#pragma unroll
        for (int mi = 0; mi < 4; mi++)
#pragma unroll
            for (int reg = 0; reg < 4; reg++) {
                int o = o0 + osub + mi * 16 + 4 * lg + reg;
                float bv = (EPI >= 1) ? bias[o] : 0.f;
#pragma unroll
                for (int ni = 0; ni < 4; ni++) {
                    int t = t0 + tsub + ni * 16 + lr;
                    size_t oidx = ((size_t)b * CQ + o) * TT + t;
                    float v = acc[mi][ni][reg] + bv;
                    if (EPI == 2) {
                        outf[oidx] = v + query[oidx] * qsc[b * CQ + o] + qsh[b * CQ + o];
                    } else if (EPI == 1) {
                        ((u8*)outb)[oidx] = f2fp8(v);
                    } else {
                        ((u16*)outb)[oidx] = f2bf(v);
                    }
                }
            }
    }
}

// ---- flash attention v13: fp8, SPLIT-T (32 t-rows/block, no redundant work),
// 2 blocks/CU, conflict-fixed swizzles. Grid (128, NB).
// 8 waves: tb = wid>>2 (16t), sub = wid&3. QK: 16t x 16s. PV: 16t x 128c.
__global__ __launch_bounds__(512, 4) void flash_kernel(
        const u8* __restrict__ qq8, const u8* __restrict__ kk8,
        const u8* __restrict__ vv8, const float* __restrict__ WM,
        u16* __restrict__ aT) {
    int T0 = blockIdx.x * 32;
    int b = blockIdx.y;
    int wid = threadIdx.x >> 6, lane = threadIdx.x & 63;
    int lr = lane & 15, lg = lane >> 4;
    int tb = wid >> 2;       // 0..1: 16 t-rows (same rows for QK and PV roles)
    int sb = wid & 3;        // QK: 16-s block
    int cq = wid & 3;        // PV: 128-c block

    __shared__ u8 K_lds[64][512];    // 32KB, 16B-chunk swizzled by (s&7)
    __shared__ u8 V_lds[512][64];    // 32KB, chunk swizzled by ((c>>2)&3)
    __shared__ u8 p_lds[32][64];     // 2KB, chunk swizzled by ((t>>2)&3)
    __shared__ float ex_max[32][4];
    __shared__ float ex_sum[32][4];

    // Q fp8 fragments: row = T0+16tb+lr, k = kc*32 + lg*8 (8B -> 2 VGPR each)
    long qf[16];
    {
        const u8* qrow = qq8 + ((size_t)b * TT + T0 + 16 * tb + lr) * 512 + lg * 8;
#pragma unroll
        for (int kc = 0; kc < 16; kc++) qf[kc] = *(const long*)(qrow + kc * 32);
    }
    f32x4 acc[8];
#pragma unroll
    for (int i = 0; i < 8; i++) acc[i] = f32x4{0.f, 0.f, 0.f, 0.f};
    float m[4], l[4];
#pragma unroll
    for (int r = 0; r < 4; r++) { m[r] = -1e30f; l[r] = 0.f; }

    const float* wmrow = WM + ((size_t)b * TT + T0 + 16 * tb + 4 * lg) * TT + 16 * sb + lr;
    const u8* kbase = kk8 + (size_t)b * TT * 512;
    const u8* vbase = vv8 + (size_t)b * CQ * TT;
    int myt = 16 * tb + 4 * lg;

    for (int s0 = 0; s0 < TT; s0 += 64) {
        __syncthreads();  // bar1: prev tile consumed
        // stage K: 2 rows (512B) per instr, 4 instr/wave; source chunk ^ (s&7)
#pragma unroll
        for (int i = 0; i < 4; i++) {
            int r0 = wid * 8 + i * 2;
            int s = r0 + (lane >> 5);
            gload_lds16(kbase + (size_t)(s0 + s) * 512 + (((lane & 31) ^ (s & 7)) << 4),
                        &K_lds[r0][0]);
        }
        // stage V: 16 rows (64B) per instr, 4 instr/wave; source chunk ^ ((c>>2)&3)
#pragma unroll
        for (int i = 0; i < 4; i++) {
            int c0 = wid * 64 + i * 16;
            int c = c0 + (lane >> 2);
            gload_lds16(vbase + (size_t)c * TT + s0 + (((lane & 3) ^ ((c >> 2) & 3)) << 4),
                        &V_lds[c0][0]);
        }
        float wmv[4];
#pragma unroll
        for (int reg = 0; reg < 4; reg++)
            wmv[reg] = wmrow[(size_t)reg * TT + s0];
        __syncthreads();  // bar2: K/V staged

        // QK: S[16t x 16s], fp8 MFMA
        f32x4 sacc = f32x4{0.f, 0.f, 0.f, 0.f};
        {
            int srow = 16 * sb + lr;
            const u8* kp = &K_lds[srow][0];
            int sw = srow & 7;
#pragma unroll
            for (int kc = 0; kc < 16; kc++) {
                long kfr = *(const long*)(kp + ((((kc << 1) | (lg >> 1)) ^ sw) << 4) + ((lg & 1) << 3));
                sacc = __builtin_amdgcn_mfma_f32_16x16x32_fp8_fp8(qf[kc], kfr, sacc, 0, 0, 0);
            }
        }
        // logits = WM*S ; partial row max over this wave's 16 s
        float lgt[4], pmax[4];
#pragma unroll
        for (int reg = 0; reg < 4; reg++) {
            float v = sacc[reg] * wmv[reg];
            lgt[reg] = v;
            pmax[reg] = v;
        }
#pragma unroll
        for (int d = 1; d < 16; d <<= 1)
#pragma unroll
            for (int reg = 0; reg < 4; reg++)
                pmax[reg] = fmaxf(pmax[reg], __shfl_xor(pmax[reg], d, 64));
        if (lr == 0) {
#pragma unroll
            for (int reg = 0; reg < 4; reg++) ex_max[myt + reg][sb] = pmax[reg];
        }
        __syncthreads();  // bar3: maxes exchanged
        float fac[4], rsum[4];
#pragma unroll
        for (int reg = 0; reg < 4; reg++) {
            int t = myt + reg;
            f32x4 em = *(const f32x4*)&ex_max[t][0];
            float mn = fmaxf(m[reg], fmaxf(fmaxf(em[0], em[1]), fmaxf(em[2], em[3])));
            fac[reg] = __expf(m[reg] - mn);
            m[reg] = mn;
        }
#pragma unroll
        for (int reg = 0; reg < 4; reg++) {
            float p = __expf(lgt[reg] - m[reg]);
            rsum[reg] = p;
            int t = myt + reg;
            // s-chunk sb stored at LDS chunk sb ^ ((t>>2)&3)
            p_lds[t][((sb ^ ((t >> 2) & 3)) << 4) + lr] = f2fp8(p);
        }
#pragma unroll
        for (int d = 1; d < 16; d <<= 1)
#pragma unroll
            for (int reg = 0; reg < 4; reg++)
                rsum[reg] += __shfl_xor(rsum[reg], d, 64);
        if (lr == 0) {
#pragma unroll
            for (int reg = 0; reg < 4; reg++) ex_sum[myt + reg][sb] = rsum[reg];
        }
        __syncthreads();  // bar4: P + sums ready
#pragma unroll
        for (int reg = 0; reg < 4; reg++) {
            int t = myt + reg;
            f32x4 es = *(const f32x4*)&ex_sum[t][0];
            l[reg] = l[reg] * fac[reg] + es[0] + es[1] + es[2] + es[3];
        }
#pragma unroll
        for (int nc = 0; nc < 8; nc++)
#pragma unroll
            for (int reg = 0; reg < 4; reg++) acc[nc][reg] *= fac[reg];
        // PV: acc[16t x 128c] += P[16t x 64s] * V[128c x 64s], fp8 MFMA
#pragma unroll
        for (int ks = 0; ks < 2; ks++) {
            int prow = 16 * tb + lr;
            long pa = *(const long*)(&p_lds[prow][0] +
                        ((((ks << 1) | (lg >> 1)) ^ ((prow >> 2) & 3)) << 4) + ((lg & 1) << 3));
#pragma unroll
            for (int nc = 0; nc < 8; nc++) {
                int vr = cq * 128 + nc * 16 + lr;
                long vf = *(const long*)(&V_lds[vr][0] +
                            ((((ks << 1) | (lg >> 1)) ^ ((vr >> 2) & 3)) << 4) + ((lg & 1) << 3));
                acc[nc] = __builtin_amdgcn_mfma_f32_16x16x32_fp8_fp8(pa, vf, acc[nc], 0, 0, 0);
            }
        }
    }
    // epilogue: normalize + store bf16
    float inv[4];
#pragma unroll
    for (int reg = 0; reg < 4; reg++) inv[reg] = 1.f / l[reg];
#pragma unroll
    for (int nc = 0; nc < 8; nc++)
#pragma unroll
        for (int reg = 0; reg < 4; reg++) {
            int t = T0 + myt + reg;
            int c = cq * 128 + nc * 16 + lr;
            aT[((size_t)b * TT + t) * CQ + c] = f2bf(acc[nc][reg] * inv[reg]);
        }
}

extern "C" void kernel_launch(void* const* d_in, const int* in_sizes, int n_in,
                              void* d_out, int out_size, void* d_ws, size_t ws_size,
                              hipStream_t stream) {
    const float* key_feat = (const float*)d_in[0];
    const float* query    = (const float*)d_in[1];
    const float* WM       = (const float*)d_in[2];
    const float* kpw      = (const float*)d_in[3];
    const float* norm_w   = (const float*)d_in[4];
    const float* norm_b   = (const float*)d_in[5];
    const float* qkv_w    = (const float*)d_in[6];
    const float* qkv_b    = (const float*)d_in[7];
    const float* proj_w   = (const float*)d_in[8];
    const float* proj_b   = (const float*)d_in[9];
    float* out = (float*)d_out;
    char* ws = (char*)d_ws;

    u16* kdsT = (u16*)(ws);                 // [0, 8.4M)   dead after kraw gemm
    u16* kraw = (u16*)(ws + 8388608);       // [8.4, 25.2M) dead after affine#2
    u16* qnT  = (u16*)(ws + 25165824);      // dead after qkv gemms
    u16* knT  = (u16*)(ws + 41943040);      // dead after qkv gemms
    u8*  qq8  = (u8*)(ws + 58720256);       // 8.4 MB fp8
    u8*  kk8  = (u8*)(ws + 67108864);       // 8.4 MB fp8
    u8*  vv8  = (u8*)(ws + 75497472);       // 8.4 MB fp8
    u16* aT   = (u16*)(ws);                 // [0, 16.8M) over kdsT+kraw head (dead by flash)
    u16* wqkv = (u16*)(ws + 16777216);      // over kraw tail, written after affine#2
    u16* wproj= (u16*)(ws + 19922944);
    float* qsc = (float*)(ws + 109051904);
    float* qsh = qsc + NB * CQ;
    float* ksc = qsh + NB * CQ;
    float* ksh = ksc + NB * CQ;
    u16* wkp  = (u16*)(ws + 109084672);     // 256KB

    // 0. convert key_proj_w to bf16
    wconv_kernel<<<64, 256, 0, stream>>>(kpw, wkp, 512 * 256, 0);
    // 1. pool + transpose
    pool_tr_kernel<<<dim3(64, NB), 256, 0, stream>>>(key_feat, kdsT);
    // 2. k_raw = key_proj_w @ kds   (staged GEMM)
    gemm_st_kernel<0, 0, 0><<<dim3(4, 32, NB), 256, 0, stream>>>(
        wkp, kdsT, nullptr, CK, nullptr, kraw, nullptr, nullptr, nullptr, nullptr, nullptr);
    // 3. group-norm stats
    gn_stats_kernel<0><<<dim3(32, NB), 256, 0, stream>>>(query, norm_w, norm_b, qsc, qsh);
    gn_stats_kernel<1><<<dim3(32, NB), 256, 0, stream>>>(kraw, norm_w, norm_b, ksc, ksh);
    // 4. normalized, transposed activations
    affine_tr_kernel<0><<<dim3(64, 8, NB), 256, 0, stream>>>(query, qsc, qsh, qnT);
    affine_tr_kernel<1><<<dim3(64, 8, NB), 256, 0, stream>>>(kraw, ksc, ksh, knT);
    // 4b. convert qkv_w (q/k rows pre-scaled) + proj_w to bf16 (kraw now dead)
    wconv_kernel<<<768, 256, 0, stream>>>(qkv_w, wqkv, 1536 * 1024, 1024 * 1024);
    wconv_kernel<<<128, 256, 0, stream>>>(proj_w, wproj, 512 * 512, 0);
    // 5. qkv projection: qq/kk swapped -> fp8, vv -> fp8
    gemm_st_kernel<1, 1, 1><<<dim3(8, 32, NB), 256, 0, stream>>>(
        wqkv, qnT, knT, 1024, qkv_b, qq8, kk8, nullptr, nullptr, nullptr, nullptr);
    gemm_st_kernel<1, 1, 0><<<dim3(4, 32, NB), 256, 0, stream>>>(
        wqkv + (size_t)1024 * 1024, qnT, knT, 1024, qkv_b + 1024, vv8, nullptr,
        nullptr, nullptr, nullptr, nullptr);
    // 6. flash attention (v13: fp8 + split-T, 2 blocks/CU, no redundant QK)
    flash_kernel<<<dim3(128, NB), 512, 0, stream>>>(qq8, kk8, vv8, WM, aT);
    // 7. out = GN(query) + proj_w @ a + proj_b
    gemm_st_kernel<2, 0, 0><<<dim3(4, 32, NB), 256, 0, stream>>>(
        wproj, aT, nullptr, CQ, proj_b, nullptr, nullptr, out, query, qsc, qsh);
}